// Round 4
// baseline (126.711 us; speedup 1.0000x reference)
//
#include <hip/hip_runtime.h>
#include <hip/hip_bf16.h>

#define NODES 8192
#define INF_ 256
#define OUTF 128
#define LRALPHA 0.02f

typedef __bf16 bf16;
typedef bf16 bf16x4 __attribute__((ext_vector_type(4)));
typedef bf16 bf16x8 __attribute__((ext_vector_type(8)));
typedef float f32x4 __attribute__((ext_vector_type(4)));
typedef float f32x16 __attribute__((ext_vector_type(16)));
typedef int i32x4 __attribute__((ext_vector_type(4)));

// ---------------- Kernel 1: Wh = x@W1 + b1 (f32), produce WhbT(bf16) + factored exp arrays ----
__global__ __launch_bounds__(256) void gat_prep_r4(
    const float* __restrict__ x, const float* __restrict__ W1,
    const float* __restrict__ b1, const float* __restrict__ a,
    const float* __restrict__ b_att,
    bf16* __restrict__ WhbT, float* __restrict__ E1,
    float* __restrict__ E2, float* __restrict__ F1, float* __restrict__ F2)
{
    __shared__ float xsT[64][36];    // [k][row], padded
    __shared__ float ws1[64][132];   // [k][col], padded
    __shared__ float wh[32][128];    // Wh tile f32

    const int t = threadIdx.x;
    const int rbase = blockIdx.x * 32;
    const int tr = t >> 5;   // 0..7  -> rows tr*4..+3
    const int tc = t & 31;   // 0..31 -> cols tc*4..+3

    f32x4 acc[4];
    f32x4 bias = *(const f32x4*)&b1[tc * 4];
#pragma unroll
    for (int i = 0; i < 4; ++i) acc[i] = bias;

    for (int kt = 0; kt < 4; ++kt) {
        const int kb = kt * 64;
        {   // stage x tile transposed: xsT[k][r] = x[rbase+r][kb+k]
            int r = t >> 3;            // 0..31
            int kq = (t & 7) * 8;      // 0..56
            f32x4 v0 = *(const f32x4*)&x[(size_t)(rbase + r) * INF_ + kb + kq];
            f32x4 v1 = *(const f32x4*)&x[(size_t)(rbase + r) * INF_ + kb + kq + 4];
#pragma unroll
            for (int i = 0; i < 4; ++i) xsT[kq + i][r] = v0[i];
#pragma unroll
            for (int i = 0; i < 4; ++i) xsT[kq + 4 + i][r] = v1[i];
        }
        {   // stage W1 tile: ws1[k][c] = W1[kb+k][c]
            int kr = t >> 2;           // 0..63
            int cq = (t & 3) * 32;
#pragma unroll
            for (int i = 0; i < 8; ++i) {
                f32x4 v = *(const f32x4*)&W1[(size_t)(kb + kr) * OUTF + cq + i * 4];
                *(f32x4*)&ws1[kr][cq + i * 4] = v;
            }
        }
        __syncthreads();
        for (int kk = 0; kk < 64; ++kk) {
            f32x4 xa = *(const f32x4*)&xsT[kk][tr * 4];
            f32x4 wb = *(const f32x4*)&ws1[kk][tc * 4];
#pragma unroll
            for (int i = 0; i < 4; ++i)
#pragma unroll
                for (int j = 0; j < 4; ++j)
                    acc[i][j] += xa[i] * wb[j];
        }
        __syncthreads();
    }

#pragma unroll
    for (int i = 0; i < 4; ++i)
        *(f32x4*)&wh[tr * 4 + i][tc * 4] = acc[i];
    __syncthreads();

    if (t < 32) {
        float s1 = 0.f, s2 = 0.f;
        for (int c = 0; c < OUTF; ++c) {
            float v = wh[t][c];
            s1 += v * a[c];
            s2 += v * a[OUTF + c];
        }
        float fsv = s1 + b_att[0];
        int r = rbase + t;
        E1[r] = expf(fsv);
        E2[r] = expf(LRALPHA * fsv);
        F1[r] = expf(s2);
        F2[r] = expf(LRALPHA * s2);
    }

    {   // WhbT[c][node] = bf16(Wh[node][c])
        int c = t >> 1;
        int rr = (t & 1) * 16;
        bf16x8 b0, b1v;
#pragma unroll
        for (int i = 0; i < 8; ++i) b0[i] = (bf16)wh[rr + i][c];
#pragma unroll
        for (int i = 0; i < 8; ++i) b1v[i] = (bf16)wh[rr + 8 + i][c];
        *(bf16x8*)&WhbT[(size_t)c * NODES + rbase + rr] = b0;
        *(bf16x8*)&WhbT[(size_t)c * NODES + rbase + rr + 8] = b1v;
    }
}

// ---------------- Kernel 2: fused masked softmax + PV (bf16 MFMA) + elu ----------------
// 16 waves = 4 jgroups x 4 t-tiles; block owns 32 rows; jgroup owns 2048 cols, BK=128
// cols/phase (16 phases). Per phase, per wave: issue whb(p) [8x16B, L2] THEN adj(p+2)
// [4x16B, HBM]; compute_w for phase p+1 consumes adj(p+1) at vmcnt(12) — the adj and
// whb streams never drain, keeping ~192B/lane in flight (Little's law fix).
#define SOFT_BAR() do { asm volatile("s_waitcnt lgkmcnt(0)" ::: "memory"); \
                        __builtin_amdgcn_s_barrier(); } while (0)

// LDS layout (dynamic, bytes):
//   [0, 65536)          4 jgroups x 2 w-buffers x 8KB (32 rows x 256B), XOR-swizzled
//   [65536, 66048)      denred[4][32] f32
//   [66048, 98816)      F1tab[8192] f32
//   [98816, 131584)     F2tab[8192] f32
//   epilogue acc zones (12 x 4KB = 48KB) alias [66048, 115200) — tables dead by then
#define WBUF_OFF   0
#define DENRED_OFF 65536
#define F1T_OFF    66048
#define F2T_OFF    98816
#define ZONE_OFF   66048
#define SMEM2_SIZE 131584

__global__ __launch_bounds__(1024, 4) void gat_attn_r4(
    const int* __restrict__ adj,
    const bf16* __restrict__ WhbT,
    const float* __restrict__ E1, const float* __restrict__ E2,
    const float* __restrict__ F1, const float* __restrict__ F2,
    float* __restrict__ out)
{
    extern __shared__ char smem[];
    const int tid = threadIdx.x;
    const int lane = tid & 63;
    const int wv = tid >> 6;       // 0..15
    const int jg = wv >> 2;        // 0..3 : column group (2048 cols)
    const int tt = wv & 3;         // 0..3 : output col tile
    const int rbase = blockIdx.x * 32;

    char* wbufA = smem + WBUF_OFF + jg * 16384;
    char* wbufB = wbufA + 8192;
    float* denred = (float*)(smem + DENRED_OFF);
    float* F1t = (float*)(smem + F1T_OFF);
    float* F2t = (float*)(smem + F2T_OFF);

    // ---- stage F1/F2 column tables into LDS (once): 8 floats/thread/table ----
    {
        int i = tid * 8;
        *(f32x4*)&F1t[i]     = *(const f32x4*)&F1[i];
        *(f32x4*)&F1t[i + 4] = *(const f32x4*)&F1[i + 4];
        *(f32x4*)&F2t[i]     = *(const f32x4*)&F2[i];
        *(f32x4*)&F2t[i + 4] = *(const f32x4*)&F2[i + 4];
    }

    const int r8 = lane >> 3;          // 0..7
    const int c8 = lane & 7;           // 0..7 -> 16 cols at c8*16
    const int wrow = tt * 8 + r8;      // 0..31 : weight row this lane computes
    const int arow = lane & 31;        // MFMA A-row / B-col / D-col
    const int ag = lane >> 5;          // 0..1  : k lane-group

    const int gr = rbase + wrow;
    const float e1v = E1[gr];
    const float e2v = E2[gr];

    f32x16 acc;
#pragma unroll
    for (int i = 0; i < 16; ++i) acc[i] = 0.f;
    float den = 0.f;

    const int jw0 = jg * (NODES / 4);
    const size_t adj_row = (size_t)gr * NODES;
    const size_t whb_row = (size_t)(32 * tt + arow) * NODES;

    __syncthreads();   // tables staged

    // weights for 128 cols [jb, jb+128) -> row wrow of buf (XOR-swizzled)
    auto compute_w = [&](char* buf, int jb, const i32x4* av) {
        const int cb = jb + c8 * 16;
#pragma unroll
        for (int h = 0; h < 2; ++h) {
            bf16x8 wb;
#pragma unroll
            for (int q = 0; q < 2; ++q) {
                f32x4 g1 = *(const f32x4*)&F1t[cb + h * 8 + q * 4];
                f32x4 g2 = *(const f32x4*)&F2t[cb + h * 8 + q * 4];
                i32x4 am = av[h * 2 + q];
#pragma unroll
                for (int jj = 0; jj < 4; ++jj) {
                    float tv = e1v * g1[jj];                 // e^s ; s>0 <=> tv>1
                    float w = tv > 1.f ? tv : e2v * g2[jj];
                    w = am[jj] ? w : 0.f;
                    den += w;
                    wb[q * 4 + jj] = (bf16)w;
                }
            }
            const int off = (wrow * 256 + c8 * 32 + h * 16) ^ ((wrow & 7) << 4);
            *(bf16x8*)(buf + off) = wb;
        }
    };

    // ---- prologue ----
    i32x4 ca[4], na[4];
#pragma unroll
    for (int q = 0; q < 4; ++q)
        ca[q] = *(const i32x4*)&adj[adj_row + jw0 + c8 * 16 + q * 4];          // adj(0)
#pragma unroll
    for (int q = 0; q < 4; ++q)
        na[q] = *(const i32x4*)&adj[adj_row + jw0 + 128 + c8 * 16 + q * 4];    // adj(1)
    compute_w(wbufA, jw0, ca);
    SOFT_BAR();

    char* cur = wbufA;
    char* nxt = wbufB;
#pragma unroll 2
    for (int p = 0; p < 16; ++p) {
        const int jb = jw0 + p * 128;

        // 1) issue whb(p) — consumed this phase (hidden under compute_w)
        bf16x8 wc[8];
#pragma unroll
        for (int m = 0; m < 8; ++m)
            wc[m] = *(const bf16x8*)&WhbT[whb_row + jb + 16 * m + 8 * ag];

        // 2) issue adj(p+2) — consumed next phase (clamped at tail)
        const int pc = (p + 2 <= 15) ? (p + 2) : 15;
        i32x4 fa[4];
#pragma unroll
        for (int q = 0; q < 4; ++q)
            fa[q] = *(const i32x4*)&adj[adj_row + jw0 + pc * 128 + c8 * 16 + q * 4];

        // 3) weights for next phase from adj(p+1) — vmcnt keeps wc+fa in flight
        if (p < 15) compute_w(nxt, jb + 128, na);

        // 4) MFMA on current buffer
#pragma unroll
        for (int m = 0; m < 8; ++m) {
            const int aoff = (arow * 256 + m * 32 + ag * 16) ^ ((arow & 7) << 4);
            bf16x8 af = *(const bf16x8*)(cur + aoff);
            acc = __builtin_amdgcn_mfma_f32_32x32x16_bf16(af, wc[m], acc, 0, 0, 0);
        }
        SOFT_BAR();
#pragma unroll
        for (int q = 0; q < 4; ++q) { na[q] = fa[q]; }
        char* tmp = cur; cur = nxt; nxt = tmp;
    }

    // den: reduce over the 8 column-lanes (bits 0..2)
    den += __shfl_xor(den, 1);
    den += __shfl_xor(den, 2);
    den += __shfl_xor(den, 4);
    if (c8 == 0) denred[jg * 32 + wrow] = den;

    // partial acc tiles from jgroups 1..3 -> LDS zones (alias table region, dead now)
    if (jg > 0) {
        float* z = (float*)(smem + ZONE_OFF + (size_t)((jg - 1) * 4 + tt) * 4096) + lane * 16;
        *(f32x16*)z = acc;
    }
    __syncthreads();

    if (jg == 0) {
#pragma unroll
        for (int q = 0; q < 3; ++q) {
            const float* z = (const float*)(smem + ZONE_OFF + (size_t)(q * 4 + tt) * 4096) + lane * 16;
            f32x16 v = *(const f32x16*)z;
#pragma unroll
            for (int i = 0; i < 16; ++i) acc[i] += v[i];
        }
#pragma unroll
        for (int rg = 0; rg < 16; ++rg) {
            const int row = (rg & 3) + 8 * (rg >> 2) + 4 * ag;  // verified C/D mapping
            float ds = denred[row] + denred[32 + row] + denred[64 + row] + denred[96 + row];
            float v = acc[rg] / ds;
            v = v > 0.f ? v : expm1f(v);
            out[(size_t)(rbase + row) * OUTF + 32 * tt + arow] = v;
        }
    }
}

extern "C" void kernel_launch(void* const* d_in, const int* in_sizes, int n_in,
                              void* d_out, int out_size, void* d_ws, size_t ws_size,
                              hipStream_t stream) {
    const float* x     = (const float*)d_in[0];
    const int*   adj   = (const int*)d_in[1];
    const float* W1    = (const float*)d_in[2];
    const float* b1    = (const float*)d_in[3];
    const float* a     = (const float*)d_in[4];
    const float* b_att = (const float*)d_in[5];
    float* out = (float*)d_out;

    char* ws = (char*)d_ws;
    bf16* WhbT = (bf16*)ws;                                   // 2 MB
    float* E1 = (float*)(ws + (size_t)2 * 1024 * 1024);
    float* E2 = E1 + NODES;
    float* F1 = E2 + NODES;
    float* F2 = F1 + NODES;

    hipLaunchKernelGGL(gat_prep_r4, dim3(NODES / 32), dim3(256), 0, stream,
                       x, W1, b1, a, b_att, WhbT, E1, E2, F1, F2);

    hipLaunchKernelGGL(gat_attn_r4, dim3(NODES / 32), dim3(1024), SMEM2_SIZE, stream,
                       adj, WhbT, E1, E2, F1, F2, out);
}